// Round 10
// baseline (158.883 us; speedup 1.0000x reference)
//
#include <hip/hip_runtime.h>
#include <cstdint>
#include <cstddef>

#define N_CLS 80
#define TOPK 1000
#define POOL_N 2048
#define MCAP 512
#define BSTR 516   // word-major bitmat: ldsB[w*BSTR + row], padded stride
#define BD 1024
#define DTB 128

// ---------------- K1: decode + score + per-class binning -------------------
// Identical to rounds 7-9 (bit-exact, absmax 0.0; no x[80] spill).
__global__ __launch_bounds__(DTB) void decode_kernel(
    const float* __restrict__ reg, const float* __restrict__ obj,
    const float* __restrict__ cls, const float* __restrict__ grid,
    const float* __restrict__ anch, const float* __restrict__ strd,
    float* __restrict__ boxes, uint2* __restrict__ scs,
    int* __restrict__ gcnt, uint2* __restrict__ gpool, int N) {
  __shared__ __align__(16) float tile[DTB * 84];
  const int tb = blockIdx.x * DTB;
  const int na = min(DTB, N - tb);
  const int nf4 = na * 20;
  const float4* cg = (const float4*)cls + (size_t)tb * 20;
  float4* tf4 = (float4*)tile;
  for (int j = threadIdx.x; j < nf4; j += DTB) {
    int a = j / 20;
    int p = j - a * 20;
    tf4[a * 21 + p] = cg[j];
  }
  __syncthreads();

  const int t = threadIdx.x;
  const int i = tb + t;
  if (i >= N) return;

  const float4 r = ((const float4*)reg)[i];
  const float2 g = ((const float2*)grid)[i];
  const float2 aw = ((const float2*)anch)[i];
  const float st = strd[i];

  float cx = (1.0f / (1.0f + expf(-r.x)) + g.x) * st;
  float cy = (1.0f / (1.0f + expf(-r.y)) + g.y) * st;
  float w = expf(r.z) * aw.x;
  float h = expf(r.w) * aw.y;
  float b0 = fminf(fmaxf((cx - 0.5f * w) / 640.0f, 0.0f), 1.0f);
  float b1 = fminf(fmaxf((cy - 0.5f * h) / 640.0f, 0.0f), 1.0f);
  float b2 = fminf(fmaxf((cx + 0.5f * w) / 640.0f, 0.0f), 1.0f);
  float b3 = fminf(fmaxf((cy + 0.5f * h) / 640.0f, 0.0f), 1.0f);
  float4 bo; bo.x = b0; bo.y = b1; bo.z = b2; bo.w = b3;
  ((float4*)boxes)[i] = bo;

  const float4* row = tf4 + t * 21;

  float mx;
  {
    float4 v = row[0];
    mx = v.x;
    mx = fmaxf(mx, v.y); mx = fmaxf(mx, v.z); mx = fmaxf(mx, v.w);
#pragma unroll
    for (int q = 1; q < N_CLS / 4; ++q) {
      float4 u = row[q];
      mx = fmaxf(mx, u.x); mx = fmaxf(mx, u.y);
      mx = fmaxf(mx, u.z); mx = fmaxf(mx, u.w);
    }
  }
  float s = 0.0f;
#pragma unroll
  for (int q = 0; q < N_CLS / 4; ++q) {
    float4 u = row[q];
    s += expf(u.x - mx); s += expf(u.y - mx);
    s += expf(u.z - mx); s += expf(u.w - mx);
  }
  float sig = 1.0f / (1.0f + expf(-obj[i]));
  float best = -1.0f; int bc = 0;
#pragma unroll
  for (int q = 0; q < N_CLS / 4; ++q) {
    float4 u = row[q];
    float e0 = expf(u.x - mx), e1 = expf(u.y - mx);
    float e2 = expf(u.z - mx), e3 = expf(u.w - mx);
    float q0 = sig * (e0 / s);
    if (q0 > best) { best = q0; bc = 4 * q + 0; }
    float q1 = sig * (e1 / s);
    if (q1 > best) { best = q1; bc = 4 * q + 1; }
    float q2 = sig * (e2 / s);
    if (q2 > best) { best = q2; bc = 4 * q + 2; }
    float q3 = sig * (e3 / s);
    if (q3 > best) { best = q3; bc = 4 * q + 3; }
  }
  scs[i] = make_uint2(__float_as_uint(best), (unsigned)bc);
  if (best >= 0.001f) {
    int p = atomicAdd(&gcnt[bc], 1);
    if (p < POOL_N) gpool[bc * POOL_N + p] = make_uint2(__float_as_uint(best), (unsigned)i);
  }
}

__device__ __forceinline__ unsigned long long kinit(int w, int m) {
  int lo = w << 6;
  return (m <= lo) ? 0ULL : ((m - lo >= 64) ? ~0ULL : ((1ULL << (m - lo)) - 1ULL));
}

// ---- K2 (fused): per-class rank sort + fillers + build + greedy + out -----
__global__ __launch_bounds__(BD, 4) void nms_kernel(
    const float* __restrict__ boxes, const uint2* __restrict__ scs,
    const int* __restrict__ gcnt, const uint2* __restrict__ gpool,
    float* __restrict__ out, int N) {
  const int c = blockIdx.x;
  const int tid = threadIdx.x;

  __shared__ uint2 pool[POOL_N];                     // 16 KB
  __shared__ float svals[TOPK];                      // 4 KB
  __shared__ int sidx[TOPK];                         // 4 KB
  __shared__ __align__(16) float4 bxyz[TOPK];        // 16 KB
  __shared__ __align__(16) unsigned long long ldsB[8 * BSTR];  // 33 KB word-major
  __shared__ unsigned char kp[TOPK];                 // fallback only
  __shared__ unsigned long long kpw[8];
  __shared__ unsigned long long nzw[8];              // per-row nonzero bitmap
  __shared__ int wsum[BD / 64 + 1];

  // zero the bitmat early; the collect->sort barrier covers it. Unwritten
  // words stay 0 => scan may apply all 8 words unconditionally.
  for (int u = tid; u < 8 * BSTR; u += BD) ldsB[u] = 0ULL;

  const int cnt = min(gcnt[c], POOL_N);
  const int m = min(cnt, TOPK);
  for (int p = tid; p < cnt; p += BD) pool[p] = gpool[c * POOL_N + p];
  __syncthreads();

  // rank sort, 2 elements per lane: halves the per-wave broadcast k-loop
  // traffic through the LDS pipe. Value desc, ties -> index asc
  // (== jax.lax.top_k order); total order => independent of bin order.
  {
    const int e0 = 2 * tid, e1 = 2 * tid + 1;   // 2*BD = 2048 >= POOL_N
    if (e0 < cnt) {
      uint2 m0 = pool[e0];
      uint2 m1 = pool[(e1 < cnt) ? e1 : e0];
      float v0 = __uint_as_float(m0.x), v1 = __uint_as_float(m1.x);
      int i0 = (int)m0.y, i1 = (int)m1.y;
      int r0 = 0, r1 = 0;
#pragma unroll 4
      for (int k = 0; k < cnt; ++k) {
        uint2 q = pool[k];                      // wave-uniform -> broadcast
        float vk = __uint_as_float(q.x);
        int ik = (int)q.y;
        r0 += (int)((vk > v0) || (vk == v0 && ik < i0));
        r1 += (int)((vk > v1) || (vk == v1 && ik < i1));
      }
      if (r0 < TOPK) { svals[r0] = v0; sidx[r0] = i0; }
      if (e1 < cnt && r1 < TOPK) { svals[r1] = v1; sidx[r1] = i1; }
    }
  }
  __syncthreads();

  // fillers: lowest-index non-matching anchors, ascending. ONE pass over the
  // first BD=1024 anchors (positives in any prefix <= m => enough fillers).
  const int M = TOPK - m;
  if (M > 0) {
    int i = tid;
    bool f = false;
    if (i < N) {
      uint2 sc = scs[i];
      f = !((int)sc.y == c && __uint_as_float(sc.x) >= 0.001f);
    }
    unsigned long long mk = __ballot(f ? 1 : 0);
    int lane = tid & 63, wv = tid >> 6;
    int pre = __popcll(mk & ((1ULL << lane) - 1ULL));
    if (lane == 0) wsum[wv] = __popcll(mk);
    __syncthreads();
    if (tid == 0) {
      int acc = 0;
      for (int wq = 0; wq < BD / 64; ++wq) { int t2 = wsum[wq]; wsum[wq] = acc; acc += t2; }
    }
    __syncthreads();
    int pos = wsum[wv] + pre;
    if (f && pos < M) sidx[m + pos] = i;
  }
  __syncthreads();

  // gather boxes into LDS
  const float4* bf4 = (const float4*)boxes;
  for (int t = tid; t < TOPK; t += BD) bxyz[t] = bf4[sidx[t]];
  __syncthreads();

  const int W = (m + 63) >> 6;
  const bool fast = (m > 0) && (m <= MCAP);

  if (fast) {
    // build upper-triangle iou>0.6 bitmask, word-major ldsB[w][row].
    // 4-rows-per-lane register tile: each broadcast bxyz[j] read yields 4
    // IoUs (was 1) -> ~2.3x fewer LDS reads in the dominant phase.
    // Division kept verbatim (bit-exact keep decisions at the 0.6 boundary).
    const int nRG = (m + 255) >> 8;           // 256-row groups
    const int ngroups = W * nRG;
    const int wv = tid >> 6, lane = tid & 63;
    for (int g = wv; g < ngroups; g += BD / 64) {
      const int w = g / nRG;
      const int r0 = (g - w * nRG) << 8;
      const int j0 = w << 6;
      const int jend = min(j0 + 64, m);
      const int rA = r0 + lane, rB = rA + 64, rC = rA + 128, rD = rA + 192;
      const float4 bA = bxyz[rA], bB = bxyz[rB & (TOPK - 1) ? rB : rB],
                   bC = bxyz[rC], bD = bxyz[rD];
      const float aA = (bA.z - bA.x) * (bA.w - bA.y);
      const float aB = (bB.z - bB.x) * (bB.w - bB.y);
      const float aC = (bC.z - bC.x) * (bC.w - bC.y);
      const float aD = (bD.z - bD.x) * (bD.w - bD.y);
      unsigned long long sA = 0, sB = 0, sC = 0, sD = 0;
      for (int j = j0; j < jend; ++j) {
        float4 jb = bxyz[j];                   // wave-uniform -> broadcast
        float aj = (jb.z - jb.x) * (jb.w - jb.y);
        unsigned long long bit = 1ULL << (j - j0);
        {
          float xx1 = fmaxf(bA.x, jb.x), yy1 = fmaxf(bA.y, jb.y);
          float xx2 = fminf(bA.z, jb.z), yy2 = fminf(bA.w, jb.w);
          float ww = fmaxf(1e-28f, xx2 - xx1), hh = fmaxf(1e-28f, yy2 - yy1);
          float inter = ww * hh;
          if (inter / (aA + aj - inter + 1e-14f) > 0.6f) sA |= bit;
        }
        {
          float xx1 = fmaxf(bB.x, jb.x), yy1 = fmaxf(bB.y, jb.y);
          float xx2 = fminf(bB.z, jb.z), yy2 = fminf(bB.w, jb.w);
          float ww = fmaxf(1e-28f, xx2 - xx1), hh = fmaxf(1e-28f, yy2 - yy1);
          float inter = ww * hh;
          if (inter / (aB + aj - inter + 1e-14f) > 0.6f) sB |= bit;
        }
        {
          float xx1 = fmaxf(bC.x, jb.x), yy1 = fmaxf(bC.y, jb.y);
          float xx2 = fminf(bC.z, jb.z), yy2 = fminf(bC.w, jb.w);
          float ww = fmaxf(1e-28f, xx2 - xx1), hh = fmaxf(1e-28f, yy2 - yy1);
          float inter = ww * hh;
          if (inter / (aC + aj - inter + 1e-14f) > 0.6f) sC |= bit;
        }
        {
          float xx1 = fmaxf(bD.x, jb.x), yy1 = fmaxf(bD.y, jb.y);
          float xx2 = fminf(bD.z, jb.z), yy2 = fminf(bD.w, jb.w);
          float ww = fmaxf(1e-28f, xx2 - xx1), hh = fmaxf(1e-28f, yy2 - yy1);
          float inter = ww * hh;
          if (inter / (aD + aj - inter + 1e-14f) > 0.6f) sD |= bit;
        }
      }
      // per-row masking + conditional write (upper triangle only).
      // diagonal word: keep only bits j > row; (2ULL<<63)==0 -> mask all.
#define WR(RR, SS)                                                      \
      if ((RR) < m && w >= ((RR) >> 6)) {                               \
        unsigned long long s_ = (SS);                                   \
        if (((RR) >> 6) == w) s_ &= ~((2ULL << ((RR) - j0)) - 1ULL);    \
        ldsB[w * BSTR + (RR)] = s_;                                     \
      }
      WR(rA, sA) WR(rB, sB) WR(rC, sC) WR(rD, sD)
#undef WR
    }
    __syncthreads();

    // nz summary: bit per row, set iff the row has any suppression bit.
    if (tid < 512) {
      bool any = false;
      if (tid < m) {
        for (int u = 0; u < W; ++u) any |= (ldsB[u * BSTR + tid] != 0ULL);
      }
      unsigned long long bl = __ballot(any ? 1 : 0);
      if ((tid & 63) == 0) nzw[tid >> 6] = bl;
    }
    __syncthreads();

    // serial greedy scan, nz-skip + speculative next-row prefetch (round 9).
    if (tid == 0) {
      unsigned long long km[8];
#pragma unroll
      for (int u = 0; u < 8; ++u) km[u] = kinit(u, m);
      for (int w = 0; w < 8; ++w) {
        if ((w << 6) >= m) break;
        const unsigned long long nzm = nzw[w];
        unsigned long long cand = km[w] & nzm;
        if (!cand) continue;
        int b = __ffsll(cand) - 1;
        unsigned long long cur[8];
#pragma unroll
        for (int u = 0; u < 8; ++u) cur[u] = ldsB[u * BSTR + (w << 6) + b];
        while (b >= 0) {
          unsigned long long done = (b >= 63) ? ~0ULL : ((2ULL << b) - 1ULL);
          unsigned long long spec = cand & ~done;   // pre-apply guess
          int nb = -1;
          unsigned long long pre[8];
          if (spec) {
            nb = __ffsll(spec) - 1;
#pragma unroll
            for (int u = 0; u < 8; ++u) pre[u] = ldsB[u * BSTR + (w << 6) + nb];
          }
#pragma unroll
          for (int u = 0; u < 8; ++u) km[u] &= ~cur[u];
          cand = km[w] & nzm & ~done;
          if (!cand) break;
          int b2 = __ffsll(cand) - 1;
          if (b2 == nb) {
#pragma unroll
            for (int u = 0; u < 8; ++u) cur[u] = pre[u];
          } else {
#pragma unroll
            for (int u = 0; u < 8; ++u) cur[u] = ldsB[u * BSTR + (w << 6) + b2];
          }
          b = b2;
        }
      }
#pragma unroll
      for (int u = 0; u < 8; ++u) kpw[u] = km[u];
    }
    __syncthreads();
  } else {
    // fallback (m == 0 or m > MCAP): serial barrier loop — always correct
    for (int t = tid; t < TOPK; t += BD) kp[t] = (t < m) ? 1 : 0;
    __syncthreads();
    for (int i = 0; i < m; ++i) {
      if (kp[i]) {
        float4 rb = bxyz[i];
        float ai = (rb.z - rb.x) * (rb.w - rb.y);
        for (int j = i + 1 + tid; j < m; j += BD) {
          if (kp[j]) {
            float4 jb = bxyz[j];
            float aj = (jb.z - jb.x) * (jb.w - jb.y);
            float xx1 = fmaxf(rb.x, jb.x), yy1 = fmaxf(rb.y, jb.y);
            float xx2 = fminf(rb.z, jb.z), yy2 = fminf(rb.w, jb.w);
            float ww = fmaxf(1e-28f, xx2 - xx1), hh = fmaxf(1e-28f, yy2 - yy1);
            float inter = ww * hh;
            float iou = inter / (ai + aj - inter + 1e-14f);
            if (iou > 0.6f) kp[j] = 0;
          }
        }
      }
      __syncthreads();
    }
  }

  // outputs: boxes [80,1000,4], scores*keep [80,1000], keep [80,1000]
  float* outB = out;
  float* outS = out + N_CLS * TOPK * 4;
  float* outK = outS + N_CLS * TOPK;
  for (int t = tid; t < TOPK; t += BD) {
    float k = 0.0f;
    if (t < m)
      k = fast ? (float)((kpw[t >> 6] >> (t & 63)) & 1ULL) : (float)kp[t];
    float v = (t < m) ? svals[t] : -1.0f;
    ((float4*)outB)[c * TOPK + t] = bxyz[t];
    outS[c * TOPK + t] = v * k;
    outK[c * TOPK + t] = k;
  }
}

extern "C" void kernel_launch(void* const* d_in, const int* in_sizes, int n_in,
                              void* d_out, int out_size, void* d_ws, size_t ws_size,
                              hipStream_t stream) {
  const float* reg  = (const float*)d_in[0];
  const float* obj  = (const float*)d_in[1];
  const float* cls  = (const float*)d_in[2];
  const float* grid = (const float*)d_in[3];
  const float* anch = (const float*)d_in[4];
  const float* strd = (const float*)d_in[5];
  const int N = in_sizes[0] / 4;  // 25200

  char* w8 = (char*)d_ws;
  size_t off = 0;
  float* boxes = (float*)(w8 + off); off += (size_t)N * 16;
  uint2* scs   = (uint2*)(w8 + off); off += (size_t)N * 8;
  int* gcnt    = (int*)(w8 + off);   off += 512;            // 80 ints, padded
  uint2* gpool = (uint2*)(w8 + off); off += (size_t)N_CLS * POOL_N * 8;
  float* out = (float*)d_out;

  hipMemsetAsync(gcnt, 0, N_CLS * sizeof(int), stream);
  decode_kernel<<<(N + DTB - 1) / DTB, DTB, 0, stream>>>(
      reg, obj, cls, grid, anch, strd, boxes, scs, gcnt, gpool, N);
  nms_kernel<<<N_CLS, BD, 0, stream>>>(boxes, scs, gcnt, gpool, out, N);
}

// Round 11
// 145.732 us; speedup vs baseline: 1.0902x; 1.0902x over previous
//
#include <hip/hip_runtime.h>
#include <cstdint>
#include <cstddef>

#define N_CLS 80
#define TOPK 1000
#define POOL_N 2048
#define MCAP 512
#define BSTR 516   // word-major bitmat: ldsB[w*BSTR + row], padded stride
#define BD 1024
#define DTB 128

// ---------------- K1: decode + score + per-class binning -------------------
// Identical to rounds 7-10 (bit-exact, absmax 0.0; no x[80] spill).
__global__ __launch_bounds__(DTB) void decode_kernel(
    const float* __restrict__ reg, const float* __restrict__ obj,
    const float* __restrict__ cls, const float* __restrict__ grid,
    const float* __restrict__ anch, const float* __restrict__ strd,
    float* __restrict__ boxes, uint2* __restrict__ scs,
    int* __restrict__ gcnt, uint2* __restrict__ gpool, int N) {
  __shared__ __align__(16) float tile[DTB * 84];
  const int tb = blockIdx.x * DTB;
  const int na = min(DTB, N - tb);
  const int nf4 = na * 20;
  const float4* cg = (const float4*)cls + (size_t)tb * 20;
  float4* tf4 = (float4*)tile;
  for (int j = threadIdx.x; j < nf4; j += DTB) {
    int a = j / 20;
    int p = j - a * 20;
    tf4[a * 21 + p] = cg[j];
  }
  __syncthreads();

  const int t = threadIdx.x;
  const int i = tb + t;
  if (i >= N) return;

  const float4 r = ((const float4*)reg)[i];
  const float2 g = ((const float2*)grid)[i];
  const float2 aw = ((const float2*)anch)[i];
  const float st = strd[i];

  float cx = (1.0f / (1.0f + expf(-r.x)) + g.x) * st;
  float cy = (1.0f / (1.0f + expf(-r.y)) + g.y) * st;
  float w = expf(r.z) * aw.x;
  float h = expf(r.w) * aw.y;
  float b0 = fminf(fmaxf((cx - 0.5f * w) / 640.0f, 0.0f), 1.0f);
  float b1 = fminf(fmaxf((cy - 0.5f * h) / 640.0f, 0.0f), 1.0f);
  float b2 = fminf(fmaxf((cx + 0.5f * w) / 640.0f, 0.0f), 1.0f);
  float b3 = fminf(fmaxf((cy + 0.5f * h) / 640.0f, 0.0f), 1.0f);
  float4 bo; bo.x = b0; bo.y = b1; bo.z = b2; bo.w = b3;
  ((float4*)boxes)[i] = bo;

  const float4* row = tf4 + t * 21;

  float mx;
  {
    float4 v = row[0];
    mx = v.x;
    mx = fmaxf(mx, v.y); mx = fmaxf(mx, v.z); mx = fmaxf(mx, v.w);
#pragma unroll
    for (int q = 1; q < N_CLS / 4; ++q) {
      float4 u = row[q];
      mx = fmaxf(mx, u.x); mx = fmaxf(mx, u.y);
      mx = fmaxf(mx, u.z); mx = fmaxf(mx, u.w);
    }
  }
  float s = 0.0f;
#pragma unroll
  for (int q = 0; q < N_CLS / 4; ++q) {
    float4 u = row[q];
    s += expf(u.x - mx); s += expf(u.y - mx);
    s += expf(u.z - mx); s += expf(u.w - mx);
  }
  float sig = 1.0f / (1.0f + expf(-obj[i]));
  float best = -1.0f; int bc = 0;
#pragma unroll
  for (int q = 0; q < N_CLS / 4; ++q) {
    float4 u = row[q];
    float e0 = expf(u.x - mx), e1 = expf(u.y - mx);
    float e2 = expf(u.z - mx), e3 = expf(u.w - mx);
    float q0 = sig * (e0 / s);
    if (q0 > best) { best = q0; bc = 4 * q + 0; }
    float q1 = sig * (e1 / s);
    if (q1 > best) { best = q1; bc = 4 * q + 1; }
    float q2 = sig * (e2 / s);
    if (q2 > best) { best = q2; bc = 4 * q + 2; }
    float q3 = sig * (e3 / s);
    if (q3 > best) { best = q3; bc = 4 * q + 3; }
  }
  scs[i] = make_uint2(__float_as_uint(best), (unsigned)bc);
  if (best >= 0.001f) {
    int p = atomicAdd(&gcnt[bc], 1);
    if (p < POOL_N) gpool[bc * POOL_N + p] = make_uint2(__float_as_uint(best), (unsigned)i);
  }
}

__device__ __forceinline__ unsigned long long kinit(int w, int m) {
  int lo = w << 6;
  return (m <= lo) ? 0ULL : ((m - lo >= 64) ? ~0ULL : ((1ULL << (m - lo)) - 1ULL));
}

// ---- K2 (fused): per-class rank sort + fillers + build + greedy + out -----
__global__ __launch_bounds__(BD, 4) void nms_kernel(
    const float* __restrict__ boxes, const uint2* __restrict__ scs,
    const int* __restrict__ gcnt, const uint2* __restrict__ gpool,
    float* __restrict__ out, int N) {
  const int c = blockIdx.x;
  const int tid = threadIdx.x;

  __shared__ uint2 pool[POOL_N];                     // 16 KB
  __shared__ float svals[TOPK];                      // 4 KB
  __shared__ int sidx[TOPK];                         // 4 KB
  __shared__ __align__(16) float4 bxyz[TOPK];        // 16 KB
  __shared__ __align__(16) unsigned long long ldsB[8 * BSTR];  // 33 KB word-major
  __shared__ unsigned char kp[TOPK];                 // fallback only
  __shared__ unsigned long long kpw[8];
  __shared__ unsigned long long nzw[8];              // per-row nonzero bitmap
  __shared__ int wsum[BD / 64 + 1];

  // zero the bitmat early; the collect->sort barrier covers it. Unwritten
  // words stay 0 => scan may apply all 8 words unconditionally.
  for (int u = tid; u < 8 * BSTR; u += BD) ldsB[u] = 0ULL;

  const int cnt = min(gcnt[c], POOL_N);
  const int m = min(cnt, TOPK);
  for (int p = tid; p < cnt; p += BD) pool[p] = gpool[c * POOL_N + p];
  __syncthreads();

  // rank sort, 2 elements per lane (halves per-wave broadcast k-loop VALU).
  // Value desc, ties -> index asc (== jax.lax.top_k order); total order =>
  // independent of nondeterministic bin order.
  {
    const int e0 = 2 * tid, e1 = 2 * tid + 1;   // 2*BD = 2048 >= POOL_N
    if (e0 < cnt) {
      uint2 m0 = pool[e0];
      uint2 m1 = pool[(e1 < cnt) ? e1 : e0];
      float v0 = __uint_as_float(m0.x), v1 = __uint_as_float(m1.x);
      int i0 = (int)m0.y, i1 = (int)m1.y;
      int r0 = 0, r1 = 0;
#pragma unroll 4
      for (int k = 0; k < cnt; ++k) {
        uint2 q = pool[k];                      // wave-uniform -> broadcast
        float vk = __uint_as_float(q.x);
        int ik = (int)q.y;
        r0 += (int)((vk > v0) || (vk == v0 && ik < i0));
        r1 += (int)((vk > v1) || (vk == v1 && ik < i1));
      }
      if (r0 < TOPK) { svals[r0] = v0; sidx[r0] = i0; }
      if (e1 < cnt && r1 < TOPK) { svals[r1] = v1; sidx[r1] = i1; }
    }
  }
  __syncthreads();

  // fillers: lowest-index non-matching anchors, ascending. ONE pass over the
  // first BD=1024 anchors (positives in any prefix <= m => enough fillers).
  const int M = TOPK - m;
  if (M > 0) {
    int i = tid;
    bool f = false;
    if (i < N) {
      uint2 sc = scs[i];
      f = !((int)sc.y == c && __uint_as_float(sc.x) >= 0.001f);
    }
    unsigned long long mk = __ballot(f ? 1 : 0);
    int lane = tid & 63, wv = tid >> 6;
    int pre = __popcll(mk & ((1ULL << lane) - 1ULL));
    if (lane == 0) wsum[wv] = __popcll(mk);
    __syncthreads();
    if (tid == 0) {
      int acc = 0;
      for (int wq = 0; wq < BD / 64; ++wq) { int t2 = wsum[wq]; wsum[wq] = acc; acc += t2; }
    }
    __syncthreads();
    int pos = wsum[wv] + pre;
    if (f && pos < M) sidx[m + pos] = i;
  }
  __syncthreads();

  // gather boxes into LDS
  const float4* bf4 = (const float4*)boxes;
  for (int t = tid; t < TOPK; t += BD) bxyz[t] = bf4[sidx[t]];
  __syncthreads();

  const int W = (m + 63) >> 6;
  const bool fast = (m > 0) && (m <= MCAP);

  if (fast) {
    // build upper-triangle iou>0.6 bitmask, word-major ldsB[w][row].
    // Fine-grained (row,word) tasks across all 1024 threads (r9 form —
    // thread-level balance beats LDS-traffic tricks at 1 block/CU).
    const int tasks = m * W;
    for (int q = tid; q < tasks; q += BD) {
      int w = q / m;                    // adjacent threads -> adjacent rows
      int row = q - w * m;              // => bxyz[j] broadcast in the wave
      if (w < (row >> 6)) continue;
      float4 rb = bxyz[row];
      float ai = (rb.z - rb.x) * (rb.w - rb.y);
      unsigned long long bits = 0ULL;
      int j0 = w << 6, jend = min(j0 + 64, m);
      for (int j = max(j0, row + 1); j < jend; ++j) {
        float4 jb = bxyz[j];
        float aj = (jb.z - jb.x) * (jb.w - jb.y);
        float xx1 = fmaxf(rb.x, jb.x), yy1 = fmaxf(rb.y, jb.y);
        float xx2 = fminf(rb.z, jb.z), yy2 = fminf(rb.w, jb.w);
        float ww = fmaxf(1e-28f, xx2 - xx1), hh = fmaxf(1e-28f, yy2 - yy1);
        float inter = ww * hh;
        float iou = inter / (ai + aj - inter + 1e-14f);
        if (iou > 0.6f) bits |= (1ULL << (j - j0));
      }
      ldsB[w * BSTR + row] = bits;      // consecutive rows -> 2-way (free)
    }
    __syncthreads();

    // nz summary: bit per row, set iff the row has any suppression bit.
    if (tid < 512) {
      bool any = false;
      if (tid < m) {
        for (int u = 0; u < W; ++u) any |= (ldsB[u * BSTR + tid] != 0ULL);
      }
      unsigned long long bl = __ballot(any ? 1 : 0);
      if ((tid & 63) == 0) nzw[tid >> 6] = bl;
    }
    __syncthreads();

    // serial greedy scan, nz-skip + speculative next-row prefetch (round 9).
    if (tid == 0) {
      unsigned long long km[8];
#pragma unroll
      for (int u = 0; u < 8; ++u) km[u] = kinit(u, m);
      for (int w = 0; w < 8; ++w) {
        if ((w << 6) >= m) break;
        const unsigned long long nzm = nzw[w];
        unsigned long long cand = km[w] & nzm;
        if (!cand) continue;
        int b = __ffsll(cand) - 1;
        unsigned long long cur[8];
#pragma unroll
        for (int u = 0; u < 8; ++u) cur[u] = ldsB[u * BSTR + (w << 6) + b];
        while (b >= 0) {
          unsigned long long done = (b >= 63) ? ~0ULL : ((2ULL << b) - 1ULL);
          unsigned long long spec = cand & ~done;   // pre-apply guess
          int nb = -1;
          unsigned long long pre[8];
          if (spec) {
            nb = __ffsll(spec) - 1;
#pragma unroll
            for (int u = 0; u < 8; ++u) pre[u] = ldsB[u * BSTR + (w << 6) + nb];
          }
#pragma unroll
          for (int u = 0; u < 8; ++u) km[u] &= ~cur[u];
          cand = km[w] & nzm & ~done;
          if (!cand) break;
          int b2 = __ffsll(cand) - 1;
          if (b2 == nb) {
#pragma unroll
            for (int u = 0; u < 8; ++u) cur[u] = pre[u];
          } else {
#pragma unroll
            for (int u = 0; u < 8; ++u) cur[u] = ldsB[u * BSTR + (w << 6) + b2];
          }
          b = b2;
        }
      }
#pragma unroll
      for (int u = 0; u < 8; ++u) kpw[u] = km[u];
    }
    __syncthreads();
  } else {
    // fallback (m == 0 or m > MCAP): serial barrier loop — always correct
    for (int t = tid; t < TOPK; t += BD) kp[t] = (t < m) ? 1 : 0;
    __syncthreads();
    for (int i = 0; i < m; ++i) {
      if (kp[i]) {
        float4 rb = bxyz[i];
        float ai = (rb.z - rb.x) * (rb.w - rb.y);
        for (int j = i + 1 + tid; j < m; j += BD) {
          if (kp[j]) {
            float4 jb = bxyz[j];
            float aj = (jb.z - jb.x) * (jb.w - jb.y);
            float xx1 = fmaxf(rb.x, jb.x), yy1 = fmaxf(rb.y, jb.y);
            float xx2 = fminf(rb.z, jb.z), yy2 = fminf(rb.w, jb.w);
            float ww = fmaxf(1e-28f, xx2 - xx1), hh = fmaxf(1e-28f, yy2 - yy1);
            float inter = ww * hh;
            float iou = inter / (ai + aj - inter + 1e-14f);
            if (iou > 0.6f) kp[j] = 0;
          }
        }
      }
      __syncthreads();
    }
  }

  // outputs: boxes [80,1000,4], scores*keep [80,1000], keep [80,1000]
  float* outB = out;
  float* outS = out + N_CLS * TOPK * 4;
  float* outK = outS + N_CLS * TOPK;
  for (int t = tid; t < TOPK; t += BD) {
    float k = 0.0f;
    if (t < m)
      k = fast ? (float)((kpw[t >> 6] >> (t & 63)) & 1ULL) : (float)kp[t];
    float v = (t < m) ? svals[t] : -1.0f;
    ((float4*)outB)[c * TOPK + t] = bxyz[t];
    outS[c * TOPK + t] = v * k;
    outK[c * TOPK + t] = k;
  }
}

extern "C" void kernel_launch(void* const* d_in, const int* in_sizes, int n_in,
                              void* d_out, int out_size, void* d_ws, size_t ws_size,
                              hipStream_t stream) {
  const float* reg  = (const float*)d_in[0];
  const float* obj  = (const float*)d_in[1];
  const float* cls  = (const float*)d_in[2];
  const float* grid = (const float*)d_in[3];
  const float* anch = (const float*)d_in[4];
  const float* strd = (const float*)d_in[5];
  const int N = in_sizes[0] / 4;  // 25200

  char* w8 = (char*)d_ws;
  size_t off = 0;
  float* boxes = (float*)(w8 + off); off += (size_t)N * 16;
  uint2* scs   = (uint2*)(w8 + off); off += (size_t)N * 8;
  int* gcnt    = (int*)(w8 + off);   off += 512;            // 80 ints, padded
  uint2* gpool = (uint2*)(w8 + off); off += (size_t)N_CLS * POOL_N * 8;
  float* out = (float*)d_out;

  hipMemsetAsync(gcnt, 0, N_CLS * sizeof(int), stream);
  decode_kernel<<<(N + DTB - 1) / DTB, DTB, 0, stream>>>(
      reg, obj, cls, grid, anch, strd, boxes, scs, gcnt, gpool, N);
  nms_kernel<<<N_CLS, BD, 0, stream>>>(boxes, scs, gcnt, gpool, out, N);
}